// Round 5
// baseline (604.803 us; speedup 1.0000x reference)
//
#include <hip/hip_runtime.h>
#include <math.h>

// VQ-VAE vector quantizer for MI355X.
// z: [32, 64, 64, 64] fp32 (B, C=D, H, W), embedding: [1024, 64] fp32.
// Outputs (concatenated fp32 in d_out):
//   [0 .. 8388607]  quantized, layout (b, c, h, w)
//   [8388608]       loss = L + 0.25*L, L = mean((q - z)^2)
//   [8388609]       perplexity
//   [8388610 .. ]   encoding indices (as float), 131072 of them
//
// Numerics: replicate numpy's fp32 arithmetic bit-for-bit where it affects
// argmin ordering (pairwise sums, sequential-FMA dot, op order of
// (zz+ee)-2*dot), since reference distances are quantized at ulp(64).
//
// Round 5: round 4 (1 row/thread, scalar e-broadcast) was LATENCY-bound:
// one dot per k = serial 64-FMA chain (256 cyc dep latency vs 128 cyc issue)
// with only 2 waves/SIMD (grid fixed by 1 thread/row) -> VALUBusy 59%.
// Fix: unroll k by 4 -> 4 independent FMA chains per thread. Per float4-step:
// 16 FMAs across 4 chains = 32 issue cyc vs 16 cyc/chain latency ->
// issue-bound with a single wave. e-rows remain wave-uniform -> SGPR
// broadcast loads, zero LDS in the hot loop.

#define NROWS 131072
#define KCODES 1024
#define DDIM 64

// Prevent fp contraction (hipcc defaults to -ffp-contract=fast which would
// fuse mul+add into fma and change bits vs numpy's separate mul/add).
__device__ __forceinline__ float nofuse(float x) {
    asm("" : "+v"(x));
    return x;
}

// numpy pairwise_sum for n=64 of terms a[i]*a[i] (8-stripe + fixed tree),
// with separate mul-round then add-round per term.
template <typename F>
__device__ __forceinline__ float pairwise64_sq(F load) {
    float r[8];
#pragma unroll
    for (int j = 0; j < 8; j++) {
        float v = load(j);
        r[j] = nofuse(v * v);
    }
#pragma unroll
    for (int i = 8; i < 64; i += 8) {
#pragma unroll
        for (int j = 0; j < 8; j++) {
            float v = load(i + j);
            r[j] = r[j] + nofuse(v * v);
        }
    }
    return ((r[0] + r[1]) + (r[2] + r[3])) + ((r[4] + r[5]) + (r[6] + r[7]));
}

// --- kernel A0: ee[k] = sum(e[k,:]**2) numpy-pairwise ---
__global__ __launch_bounds__(256) void kA0(const float* __restrict__ emb,
                                           float* __restrict__ ee) {
    int k = blockIdx.x * 256 + threadIdx.x;
    if (k >= KCODES) return;
    const float* er = emb + (size_t)k * DDIM;
    ee[k] = pairwise64_sq([&](int i) { return er[i]; });
}

// --- kernel A: fused argmin + quantized gather/store + loss + counts ---
// One thread per row n=(b,h,w); wave lanes = consecutive w -> all global
// z access coalesced. e-row addresses uniform across the wave (k-loop),
// unrolled x4 for 4 independent FMA dependency chains.
__global__ __launch_bounds__(256) void kA(const float* __restrict__ z,
                                          const float* __restrict__ emb,
                                          const float* __restrict__ ee,
                                          int* __restrict__ counts,
                                          float* __restrict__ out_idx,
                                          float* __restrict__ out_q,
                                          double* __restrict__ loss_sum) {
    __shared__ int hist[KCODES];
    __shared__ double wred[4];
    const int tid = threadIdx.x;
    const int n = blockIdx.x * 256 + tid;
    const int w = n & 63;
    const int h = (n >> 6) & 63;
    const int b = n >> 12;

    const float* zb = z + (size_t)b * 262144 + (size_t)h * 64 + w;
    float zr[64];
#pragma unroll
    for (int d = 0; d < 64; d++) zr[d] = zb[(size_t)d * 4096];

    const float zz = pairwise64_sq([&](int i) { return zr[i]; });

#pragma unroll
    for (int s = 0; s < 4; s++) hist[tid + s * 256] = 0;
    __syncthreads();

    float minv = INFINITY;
    int mini = 0;
    for (int k0 = 0; k0 < KCODES; k0 += 4) {
        const float4* er0 = (const float4*)(emb + (size_t)(k0 + 0) * 64);
        const float4* er1 = (const float4*)(emb + (size_t)(k0 + 1) * 64);
        const float4* er2 = (const float4*)(emb + (size_t)(k0 + 2) * 64);
        const float4* er3 = (const float4*)(emb + (size_t)(k0 + 3) * 64);
        float dot0 = 0.0f, dot1 = 0.0f, dot2 = 0.0f, dot3 = 0.0f;
#pragma unroll
        for (int q = 0; q < 16; q++) {
            float4 e0 = er0[q], e1 = er1[q], e2 = er2[q], e3 = er3[q];
            float z0 = zr[4 * q + 0], z1 = zr[4 * q + 1];
            float z2 = zr[4 * q + 2], z3 = zr[4 * q + 3];
            // 4 independent sequential ascending-d FMA chains
            dot0 = __builtin_fmaf(z0, e0.x, dot0);
            dot1 = __builtin_fmaf(z0, e1.x, dot1);
            dot2 = __builtin_fmaf(z0, e2.x, dot2);
            dot3 = __builtin_fmaf(z0, e3.x, dot3);
            dot0 = __builtin_fmaf(z1, e0.y, dot0);
            dot1 = __builtin_fmaf(z1, e1.y, dot1);
            dot2 = __builtin_fmaf(z1, e2.y, dot2);
            dot3 = __builtin_fmaf(z1, e3.y, dot3);
            dot0 = __builtin_fmaf(z2, e0.z, dot0);
            dot1 = __builtin_fmaf(z2, e1.z, dot1);
            dot2 = __builtin_fmaf(z2, e2.z, dot2);
            dot3 = __builtin_fmaf(z2, e3.z, dot3);
            dot0 = __builtin_fmaf(z3, e0.w, dot0);
            dot1 = __builtin_fmaf(z3, e1.w, dot1);
            dot2 = __builtin_fmaf(z3, e2.w, dot2);
            dot3 = __builtin_fmaf(z3, e3.w, dot3);
        }
        // min updates in ascending-k order, strict < : first min wins
        float t0 = zz + ee[k0 + 0];
        float t1 = zz + ee[k0 + 1];
        float t2 = zz + ee[k0 + 2];
        float t3 = zz + ee[k0 + 3];
        float d0 = t0 - 2.0f * dot0;
        float d1 = t1 - 2.0f * dot1;
        float d2 = t2 - 2.0f * dot2;
        float d3 = t3 - 2.0f * dot3;
        if (d0 < minv) { minv = d0; mini = k0 + 0; }
        if (d1 < minv) { minv = d1; mini = k0 + 1; }
        if (d2 < minv) { minv = d2; mini = k0 + 2; }
        if (d3 < minv) { minv = d3; mini = k0 + 3; }
    }

    out_idx[n] = (float)mini;
    atomicAdd(&hist[mini], 1);

    // gather quantized row, store (b,c,h,w), accumulate fp64 loss
    const float4* qrow = (const float4*)(emb + (size_t)mini * 64);
    float* qb = out_q + (size_t)b * 262144 + (size_t)h * 64 + w;
    double dsum = 0.0;
#pragma unroll
    for (int q = 0; q < 16; q++) {
        float4 q4 = qrow[q];
        qb[(size_t)(4 * q + 0) * 4096] = q4.x;
        qb[(size_t)(4 * q + 1) * 4096] = q4.y;
        qb[(size_t)(4 * q + 2) * 4096] = q4.z;
        qb[(size_t)(4 * q + 3) * 4096] = q4.w;
        float d0 = q4.x - zr[4 * q + 0];
        float d1 = q4.y - zr[4 * q + 1];
        float d2 = q4.z - zr[4 * q + 2];
        float d3 = q4.w - zr[4 * q + 3];
        dsum += (double)(d0 * d0);
        dsum += (double)(d1 * d1);
        dsum += (double)(d2 * d2);
        dsum += (double)(d3 * d3);
    }
    for (int off = 32; off > 0; off >>= 1) dsum += __shfl_down(dsum, off, 64);
    __syncthreads();  // hist atomics done before flush reads
    if ((tid & 63) == 0) wred[tid >> 6] = dsum;
#pragma unroll
    for (int s = 0; s < 4; s++) {
        int slot = tid + s * 256;
        int c = hist[slot];
        if (c) atomicAdd(&counts[slot], c);
    }
    __syncthreads();
    if (tid == 0) {
        double tot = (wred[0] + wred[1]) + (wred[2] + wred[3]);
        atomicAdd(loss_sum, tot);
    }
}

// --- kernel C: loss + perplexity scalars ---
__global__ __launch_bounds__(1024) void kC(const int* __restrict__ counts,
                                           const double* __restrict__ loss_sum,
                                           float* __restrict__ out_loss,
                                           float* __restrict__ out_perp) {
    __shared__ float wr[16];
    const int tid = threadIdx.x;
    float p = (float)counts[tid] * (1.0f / 131072.0f);
    float v = p + 1e-10f;
    float term = p * logf(v);
    float s = term;
    for (int off = 32; off > 0; off >>= 1) s += __shfl_down(s, off, 64);
    if ((tid & 63) == 0) wr[tid >> 6] = s;
    __syncthreads();
    if (tid == 0) {
        float tot = 0.0f;
#pragma unroll
        for (int j = 0; j < 16; j++) tot += wr[j];
        out_perp[0] = expf(-tot);
        double L = *loss_sum / 8388608.0;
        float Lf = (float)L;
        out_loss[0] = Lf + 0.25f * Lf;
    }
}

extern "C" void kernel_launch(void* const* d_in, const int* in_sizes, int n_in,
                              void* d_out, int out_size, void* d_ws, size_t ws_size,
                              hipStream_t stream) {
    const float* z = (const float*)d_in[0];
    const float* emb = (const float*)d_in[1];
    float* out = (float*)d_out;
    float* out_q = out;                    // 8388608
    float* out_loss = out + 8388608;       // 1
    float* out_perp = out + 8388609;       // 1
    float* out_idx = out + 8388610;        // 131072

    char* ws = (char*)d_ws;
    double* loss_sum = (double*)ws;        // 8 B @ 0
    int* counts = (int*)(ws + 64);         // 4 KB @ 64
    float* ee = (float*)(ws + 64 + 4096);  // 4 KB

    hipMemsetAsync(d_ws, 0, 64 + 4096, stream);
    kA0<<<4, 256, 0, stream>>>(emb, ee);
    kA<<<512, 256, 0, stream>>>(z, emb, ee, counts, out_idx, out_q, loss_sum);
    kC<<<1, 1024, 0, stream>>>(counts, loss_sum, out_loss, out_perp);
}

// Round 6
// 281.917 us; speedup vs baseline: 2.1453x; 2.1453x over previous
//
#include <hip/hip_runtime.h>
#include <math.h>

// VQ-VAE vector quantizer for MI355X.
// z: [32, 64, 64, 64] fp32 (B, C=D, H, W), embedding: [1024, 64] fp32.
// Outputs (concatenated fp32 in d_out):
//   [0 .. 8388607]  quantized, layout (b, c, h, w)
//   [8388608]       loss = L + 0.25*L, L = mean((q - z)^2)
//   [8388609]       perplexity
//   [8388610 .. ]   encoding indices (as float), 131072 of them
//
// Numerics: replicate numpy's fp32 arithmetic bit-for-bit where it affects
// argmin ordering (pairwise sums, sequential-FMA dot, op order of
// (zz+ee)-2*dot), since reference distances are quantized at ulp(64).
//
// Round 6: rounds 4/5 (scalar e-broadcast) were SGPR-capacity/latency bound
// -> reverted. Base = round 3 (LDS 8x8 tile, 263us = 164us LDS-pipe + 125us
// VALU, ADDITIVE). This round: software-pipeline the dq loop (double-buffered
// zf/ef register sets, prefetch dq+1 ds_reads before dq's FMA burst) so the
// LDS pipe runs concurrently with the VALU. Target = max(164,125) + eps.

#define NROWS 131072
#define KCODES 1024
#define DDIM 64

// Prevent fp contraction (hipcc defaults to -ffp-contract=fast which would
// fuse mul+add into fma and change bits vs numpy's separate mul/add).
__device__ __forceinline__ float nofuse(float x) {
    asm("" : "+v"(x));
    return x;
}

// numpy pairwise_sum for n=64 of terms a[i]*a[i] (8-stripe + fixed tree),
// with separate mul-round then add-round per term.
template <typename F>
__device__ __forceinline__ float pairwise64_sq(F load) {
    float r[8];
#pragma unroll
    for (int j = 0; j < 8; j++) {
        float v = load(j);
        r[j] = nofuse(v * v);
    }
#pragma unroll
    for (int i = 8; i < 64; i += 8) {
#pragma unroll
        for (int j = 0; j < 8; j++) {
            float v = load(i + j);
            r[j] = r[j] + nofuse(v * v);
        }
    }
    return ((r[0] + r[1]) + (r[2] + r[3])) + ((r[4] + r[5]) + (r[6] + r[7]));
}

// --- kernel A0: ee[k] = sum(e[k,:]**2) numpy-pairwise ---
__global__ __launch_bounds__(256) void kA0(const float* __restrict__ emb,
                                           float* __restrict__ ee) {
    int k = blockIdx.x * 256 + threadIdx.x;
    if (k >= KCODES) return;
    const float* er = emb + (size_t)k * DDIM;
    ee[k] = pairwise64_sq([&](int i) { return er[i]; });
}

// 16 FMAs of one float4-step for an 8x8 tile slice.
#define FMA_STEP(dotv, zfv, efv)                                        \
    _Pragma("unroll") for (int r = 0; r < 8; r++)                       \
        _Pragma("unroll") for (int c = 0; c < 8; c++) {                 \
            dotv[r][c] = __builtin_fmaf(zfv[r].x, efv[c].x, dotv[r][c]);\
            dotv[r][c] = __builtin_fmaf(zfv[r].y, efv[c].y, dotv[r][c]);\
            dotv[r][c] = __builtin_fmaf(zfv[r].z, efv[c].z, dotv[r][c]);\
            dotv[r][c] = __builtin_fmaf(zfv[r].w, efv[c].w, dotv[r][c]);\
        }

// --- kernel A: per-row argmin over 1024 codes + counts + index output ---
// Block: 256 threads, 128 rows. Thread (rg,kg): rows {rg+16r}, cols {kg+16c}
// within each 128-code e-tile. 8x8 register tile, dq-loop double-buffered.
// LDS (dynamic, 70144 B): zt[128][68] @0, et[128][68] @34816, zzs @69632;
// redv/redi alias et after the k-loop.
__global__ __launch_bounds__(256, 2) void kA(const float* __restrict__ z,
                                             const float* __restrict__ emb,
                                             const float* __restrict__ ee,
                                             int* __restrict__ counts,
                                             float* __restrict__ out_idx) {
    extern __shared__ __align__(16) char sm[];
    float(*zt)[68] = (float(*)[68])sm;
    float(*et)[68] = (float(*)[68])(sm + 34816);
    float* zzs = (float*)(sm + 69632);
    float(*redv)[16] = (float(*)[16])(sm + 34816);
    int(*redi)[16] = (int(*)[16])(sm + 43008);

    const int tid = threadIdx.x;
    const int blk = blockIdx.x;       // 0..1023
    const int n0 = blk * 128;
    const int b = blk >> 5;
    const int h0 = (blk & 31) * 2;

    // stage z tile: rows j=0..127 are (h0,h0+1) x w; coalesced over j.
    const float* zb = z + (size_t)b * 262144 + (size_t)h0 * 64;
    for (int i = tid; i < 128 * 64; i += 256) {
        int d = i >> 7, j = i & 127;
        zt[j][d] = zb[(size_t)d * 4096 + j];
    }
    __syncthreads();
    if (tid < 128) {
        int w = tid;
        zzs[w] = pairwise64_sq([&](int i) { return zt[w][i]; });
    }
    __syncthreads();

    const int rg = tid & 15, kg = tid >> 4;
    float zzr[8];
#pragma unroll
    for (int r = 0; r < 8; r++) zzr[r] = zzs[rg + 16 * r];

    float minv[8];
    int mini[8];
#pragma unroll
    for (int r = 0; r < 8; r++) { minv[r] = INFINITY; mini[r] = 0; }

    for (int t = 0; t < 8; t++) {
        const int kbase = t * 128;
        __syncthreads();  // protect et from previous iteration's readers
        // stage e tile with float4: 2048 float4 / 256 threads = 8 each
        for (int i = tid; i < 128 * 16; i += 256) {
            int k = i >> 4, q = i & 15;
            *(float4*)&et[k][q * 4] =
                *(const float4*)&emb[(size_t)(kbase + k) * 64 + q * 4];
        }
        __syncthreads();

        float dot[8][8];
#pragma unroll
        for (int r = 0; r < 8; r++)
#pragma unroll
            for (int c = 0; c < 8; c++) dot[r][c] = 0.0f;

        // dq loop, software-pipelined: buffer A computes while buffer B's
        // ds_reads are in flight (and vice versa). FMA order per (r,c)
        // stays sequential ascending-d -> bit-exact.
        float4 zfA[8], efA[8], zfB[8], efB[8];
#pragma unroll
        for (int r = 0; r < 8; r++)
            zfA[r] = *(const float4*)&zt[rg + 16 * r][0];
#pragma unroll
        for (int c = 0; c < 8; c++)
            efA[c] = *(const float4*)&et[kg + 16 * c][0];

#pragma unroll
        for (int dq = 0; dq < 16; dq += 2) {
            // prefetch dq+1 into B
#pragma unroll
            for (int r = 0; r < 8; r++)
                zfB[r] = *(const float4*)&zt[rg + 16 * r][(dq + 1) * 4];
#pragma unroll
            for (int c = 0; c < 8; c++)
                efB[c] = *(const float4*)&et[kg + 16 * c][(dq + 1) * 4];
            // compute dq from A
            FMA_STEP(dot, zfA, efA)
            // prefetch dq+2 into A (compile-time guard; dq loop is unrolled)
            if (dq + 2 < 16) {
#pragma unroll
                for (int r = 0; r < 8; r++)
                    zfA[r] = *(const float4*)&zt[rg + 16 * r][(dq + 2) * 4];
#pragma unroll
                for (int c = 0; c < 8; c++)
                    efA[c] = *(const float4*)&et[kg + 16 * c][(dq + 2) * 4];
            }
            // compute dq+1 from B
            FMA_STEP(dot, zfB, efB)
        }

#pragma unroll
        for (int c = 0; c < 8; c++) {
            const int kglob = kbase + kg + 16 * c;
            const float eec = ee[kglob];
#pragma unroll
            for (int r = 0; r < 8; r++) {
                float tt = zzr[r] + eec;           // rounds at ulp(~64)
                float dv = tt - 2.0f * dot[r][c];  // 2*dot exact; one sub round
                if (dv < minv[r]) { minv[r] = dv; mini[r] = kglob; }
            }
        }
    }
    __syncthreads();  // done reading et; reuse space for reduction
#pragma unroll
    for (int r = 0; r < 8; r++) {
        redv[rg + 16 * r][kg] = minv[r];
        redi[rg + 16 * r][kg] = mini[r];
    }
    __syncthreads();
    if (tid < 128) {
        int w = tid;
        float bv = redv[w][0];
        int bi = redi[w][0];
#pragma unroll
        for (int j = 1; j < 16; j++) {
            float v = redv[w][j];
            int ix = redi[w][j];
            if (v < bv || (v == bv && ix < bi)) { bv = v; bi = ix; }
        }
        out_idx[n0 + w] = (float)bi;
        atomicAdd(&counts[bi], 1);
    }
}

// --- kernel B: gather quantized + fp64 loss accumulation ---
__global__ __launch_bounds__(256) void kB(const float* __restrict__ z,
                                          const float* __restrict__ emb,
                                          const float* __restrict__ out_idxf,
                                          float* __restrict__ out_q,
                                          double* __restrict__ loss_sum) {
    __shared__ int idx_s[64];
    __shared__ double wred[4];
    const int tid = threadIdx.x;
    const int blk = blockIdx.x;
    const int n0 = blk * 64;
    const int b = blk >> 6;
    const int h = blk & 63;
    if (tid < 64) idx_s[tid] = (int)out_idxf[n0 + tid];
    __syncthreads();
    const float* zb = z + (size_t)b * 262144 + (size_t)h * 64;
    float* qb = out_q + (size_t)b * 262144 + (size_t)h * 64;
    double dsum = 0.0;
    for (int i = tid; i < 4096; i += 256) {
        int c = i >> 6, w = i & 63;
        float q = emb[(size_t)idx_s[w] * 64 + c];
        float zv = zb[(size_t)c * 4096 + w];
        qb[(size_t)c * 4096 + w] = q;
        float df = q - zv;
        float s = df * df;
        dsum += (double)s;
    }
    for (int off = 32; off > 0; off >>= 1) dsum += __shfl_down(dsum, off, 64);
    if ((tid & 63) == 0) wred[tid >> 6] = dsum;
    __syncthreads();
    if (tid == 0) {
        double tot = (wred[0] + wred[1]) + (wred[2] + wred[3]);
        atomicAdd(loss_sum, tot);
    }
}

// --- kernel C: loss + perplexity scalars ---
__global__ __launch_bounds__(1024) void kC(const int* __restrict__ counts,
                                           const double* __restrict__ loss_sum,
                                           float* __restrict__ out_loss,
                                           float* __restrict__ out_perp) {
    __shared__ float wr[16];
    const int tid = threadIdx.x;
    float p = (float)counts[tid] * (1.0f / 131072.0f);
    float v = p + 1e-10f;
    float term = p * logf(v);
    float s = term;
    for (int off = 32; off > 0; off >>= 1) s += __shfl_down(s, off, 64);
    if ((tid & 63) == 0) wr[tid >> 6] = s;
    __syncthreads();
    if (tid == 0) {
        float tot = 0.0f;
#pragma unroll
        for (int j = 0; j < 16; j++) tot += wr[j];
        out_perp[0] = expf(-tot);
        double L = *loss_sum / 8388608.0;
        float Lf = (float)L;
        out_loss[0] = Lf + 0.25f * Lf;
    }
}

extern "C" void kernel_launch(void* const* d_in, const int* in_sizes, int n_in,
                              void* d_out, int out_size, void* d_ws, size_t ws_size,
                              hipStream_t stream) {
    const float* z = (const float*)d_in[0];
    const float* emb = (const float*)d_in[1];
    float* out = (float*)d_out;
    float* out_q = out;                    // 8388608
    float* out_loss = out + 8388608;       // 1
    float* out_perp = out + 8388609;       // 1
    float* out_idx = out + 8388610;        // 131072

    char* ws = (char*)d_ws;
    double* loss_sum = (double*)ws;        // 8 B @ 0
    int* counts = (int*)(ws + 64);         // 4 KB @ 64
    float* ee = (float*)(ws + 64 + 4096);  // 4 KB

    // Allow 70144 B dynamic LDS for kA (host-side attribute set; not a
    // stream op, so graph-capture-safe; idempotent and deterministic).
    (void)hipFuncSetAttribute((const void*)kA,
                              hipFuncAttributeMaxDynamicSharedMemorySize,
                              70144);

    hipMemsetAsync(d_ws, 0, 64 + 4096, stream);
    kA0<<<4, 256, 0, stream>>>(emb, ee);
    kA<<<1024, 256, 70144, stream>>>(z, emb, ee, counts, out_idx);
    kB<<<2048, 256, 0, stream>>>(z, emb, out_idx, out_q, loss_sum);
    kC<<<1, 1024, 0, stream>>>(counts, loss_sum, out_loss, out_perp);
}